// Round 18
// baseline (232.069 us; speedup 1.0000x reference)
//
#include <hip/hip_runtime.h>
#include <cstdint>

#define S_LEN 1024
#define C_DIM 2048
#define NH    16
#define NHK   4
#define HD    128
#define ROT   32
#define SCALE 0.08838834764831845f  // 1/sqrt(128)

typedef __bf16 bf16x8 __attribute__((ext_vector_type(8)));
typedef float floatx4 __attribute__((ext_vector_type(4)));
typedef float floatx16 __attribute__((ext_vector_type(16)));
typedef unsigned short ushortx8 __attribute__((ext_vector_type(8)));

__device__ __forceinline__ unsigned short f2bf(float f) {
  union { float f; uint32_t u; } x; x.f = f;
  uint32_t r = (x.u + 0x7fffu + ((x.u >> 16) & 1u)) >> 16;
  return (unsigned short)r;
}
__device__ __forceinline__ float bf2f(unsigned short v) {
  union { uint32_t u; float f; } x; x.u = (uint32_t)v << 16; return x.f;
}

__device__ __forceinline__ void async_copy16(const unsigned short* g, unsigned short* l) {
  __builtin_amdgcn_global_load_lds(
      (const __attribute__((address_space(1))) void*)g,
      (__attribute__((address_space(3))) void*)l,
      16, 0, 0);
}

#define WAIT_VM(N) asm volatile("s_waitcnt vmcnt(" #N ")" ::: "memory")

// Barrier that waits ONLY on LDS ops (lgkmcnt) before syncing; DMA (vmcnt)
// stays in flight across it unless explicitly counted beforehand.
__device__ __forceinline__ void bar_lds_only() {
  asm volatile("s_waitcnt lgkmcnt(0)" ::: "memory");
  __builtin_amdgcn_s_barrier();
}

// Bank swizzle: separates rows {r, r+8, r+16, r+24} -> conflict-free (R7: took
// SQ_LDS_BANK_CONFLICT 3.9M -> 0). Bijective per row.
__device__ __forceinline__ int swz8(int row) { return (row ^ (row >> 3)) & 7; }

// ---------------- merged prep: weight cast + x transpose (1 dispatch) -------
__global__ __launch_bounds__(256)
void prep_kernel(const float* __restrict__ qw, const float* __restrict__ kw,
                 const float* __restrict__ vw, const float* __restrict__ ow,
                 unsigned short* __restrict__ wout,
                 const float* __restrict__ x, unsigned short* __restrict__ xT) {
  __shared__ float t[32][33];
  int bid = blockIdx.x;
  if (bid < 14336) {
    const int NQ = 4096 * 2048 / 4, NK = 512 * 2048 / 4, NV = 512 * 2048 / 4;
    int i = bid * 256 + threadIdx.x;
    const float* src; int j;
    if (i < NQ) { src = qw; j = i; }
    else if (i < NQ + NK) { src = kw; j = i - NQ; }
    else if (i < NQ + NK + NV) { src = vw; j = i - NQ - NK; }
    else { src = ow; j = i - NQ - NK - NV; }
    float4 v = ((const float4*)src)[j];
    ushort4 o;
    o.x = f2bf(v.x); o.y = f2bf(v.y); o.z = f2bf(v.z); o.w = f2bf(v.w);
    ((ushort4*)wout)[i] = o;
  } else {
    int b2 = bid - 14336;
    int st = b2 & 31, ct = b2 >> 5;
    int c = threadIdx.x & 31, rq = threadIdx.x >> 5;
#pragma unroll
    for (int i = 0; i < 4; ++i) {
      int r = rq + i * 8;
      t[r][c] = x[(size_t)(ct * 32 + r) * S_LEN + st * 32 + c];
    }
    __syncthreads();
#pragma unroll
    for (int i = 0; i < 4; ++i) {
      int r = rq + i * 8;
      xT[(size_t)(st * 32 + r) * C_DIM + ct * 32 + c] = f2bf(t[c][r]);
    }
  }
}

// ---------------- RMSNorm+RoPE epilogue (4-wave core, 2 ni per wave) --------
__device__ __forceinline__ void norm_rope_epi4(
    floatx16 (&acc)[2], float (*pp)[64],
    const float* __restrict__ w, const int* __restrict__ pos_ids,
    const float* __restrict__ cosc, const float* __restrict__ sinc,
    unsigned short* __restrict__ outp,  // (S, D) for this head
    int wave, int lane, int wm, int scol0) {
  int l31 = lane & 31, half = lane >> 5;
#pragma unroll
  for (int ni = 0; ni < 2; ++ni) {
    float s = 0.f;
#pragma unroll
    for (int reg = 0; reg < 16; ++reg) { float v = acc[ni][reg]; s += v * v; }
    s += __shfl_xor(s, 32);
    if (half == 0) pp[wave][ni * 32 + l31] = s;
  }
  __syncthreads();
#pragma unroll
  for (int ni = 0; ni < 2; ++ni) {
    int ci = ni * 32 + l31;
    float tot = pp[0][ci] + pp[1][ci] + pp[2][ci] + pp[3][ci];
    float rn = rsqrtf(tot * (1.0f / 128.0f) + 1e-6f);
    int scol = scol0 + ni * 32 + l31;
    int pos = pos_ids[scol];
    bool rope = (wm == 0);  // wave 0 covers d 0..31
#pragma unroll
    for (int g = 0; g < 4; ++g) {
      int dbase = wm + half * 4 + g * 8;
      ushort4 o;
#pragma unroll
      for (int rr = 0; rr < 4; ++rr) {
        int reg = g * 4 + rr;
        int d = dbase + rr;
        float v = acc[ni][reg] * rn * (1.0f + w[d]);
        if (rope) {
          float cv = cosc[pos * ROT + d], sv = sinc[pos * ROT + d];
          int d2 = (d < 16) ? d + 16 : d - 16;
          float pv = acc[ni][reg ^ 8] * rn * (1.0f + w[d2]);  // row +-16
          v = v * cv + ((d < 16) ? -pv : pv) * sv;
        }
        ((unsigned short*)&o)[rr] = f2bf(v);
      }
      *(ushort4*)&outp[(size_t)scol * HD + dbase] = o;
    }
  }
}

// ---------------- QKV GEMM 128x64, 4 waves, DMA-staged 2-buffer (R12) -------
// Round-25: + T5 s_setprio around the MFMA cluster. 3 independent blocks/CU
// with drifting barrier phases -> scheduler has waves at different phases to
// arbitrate (m191/m224's documented applicability regime; null only on
// single-block lockstep grids). Pure hint, no correctness impact.
#define STAGE_QKV4(B_, KT)                                                     \
  { _Pragma("unroll")                                                          \
    for (int i = 0; i < 4; ++i) {                                              \
      int row = wm + i * 8 + sr;                                               \
      async_copy16(Ag + (size_t)row * C_DIM + (KT) + (sc ^ swz8(row)) * 8,     \
                   &Asm[B_][(wm + i * 8) * 64]);                               \
    }                                                                          \
    _Pragma("unroll")                                                          \
    for (int i = 0; i < 2; ++i) {                                              \
      int row = wave * 16 + i * 8 + sr;                                        \
      async_copy16(Bg + (size_t)row * C_DIM + (KT) + (sc ^ swz8(row)) * 8,     \
                   &Bsm[B_][(wave * 16 + i * 8) * 64]);                        \
    } }

__global__ __launch_bounds__(256, 3)
void gemm_qkv_fused(const unsigned short* __restrict__ A,
                    const unsigned short* __restrict__ BT,
                    const float* __restrict__ qw, const float* __restrict__ kw,
                    const int* __restrict__ pos_ids,
                    const float* __restrict__ cosc, const float* __restrict__ sinc,
                    unsigned short* __restrict__ qb, unsigned short* __restrict__ kbuf,
                    unsigned short* __restrict__ vTb, unsigned short* __restrict__ sgb) {
  __shared__ unsigned short Asm[2][128 * 64];
  __shared__ unsigned short Bsm[2][64 * 64];
  __shared__ float pp[4][64];
  int tid = threadIdx.x, wave = tid >> 6, lane = tid & 63;
  int l31 = lane & 31, half = lane >> 5;
  int wm = wave * 32;
  int m0 = blockIdx.x * 128, n0 = blockIdx.y * 64;
  int sr = lane >> 3, sc = lane & 7;
  const unsigned short* Ag = A + (size_t)m0 * C_DIM;
  const unsigned short* Bg = BT + (size_t)n0 * C_DIM;
  int aswz = swz8(wm + l31);
  int bswz0 = swz8(l31), bswz1 = swz8(32 + l31);
  floatx16 acc[2];
  acc[0] = (floatx16)0.f; acc[1] = (floatx16)0.f;

  STAGE_QKV4(0, 0)
  STAGE_QKV4(1, 64)

  for (int t = 0; t < 32; ++t) {
    int b = t & 1;
    if (t < 31) { WAIT_VM(6); } else { WAIT_VM(0); }  // tile t landed; t+1 flying
    __builtin_amdgcn_s_barrier();
    __builtin_amdgcn_s_setprio(1);
#pragma unroll
    for (int kb = 0; kb < 4; ++kb) {
      int c2 = (kb << 1) | half;
      bf16x8 av  = *(const bf16x8*)&Asm[b][(wm + l31) * 64 + ((c2 ^ aswz) << 3)];
      bf16x8 b0v = *(const bf16x8*)&Bsm[b][l31 * 64 + ((c2 ^ bswz0) << 3)];
      bf16x8 b1v = *(const bf16x8*)&Bsm[b][(32 + l31) * 64 + ((c2 ^ bswz1) << 3)];
      acc[0] = __builtin_amdgcn_mfma_f32_32x32x16_bf16(av, b0v, acc[0], 0, 0, 0);
      acc[1] = __builtin_amdgcn_mfma_f32_32x32x16_bf16(av, b1v, acc[1], 0, 0, 0);
    }
    __builtin_amdgcn_s_setprio(0);
    bar_lds_only();                    // all waves done reading buf b
    if (t < 30) STAGE_QKV4(b, (t + 2) * 64)
  }

  int scol0 = n0;
  int ty = blockIdx.x;
  if (ty < 32) {
    int h = ty >> 1;
    if ((ty & 1) == 0) {
      norm_rope_epi4(acc, pp, qw, pos_ids, cosc, sinc,
                     qb + (size_t)h * S_LEN * HD, wave, lane, wm, scol0);
    } else {
#pragma unroll
      for (int ni = 0; ni < 2; ++ni) {
        int scol = scol0 + ni * 32 + l31;
#pragma unroll
        for (int g = 0; g < 4; ++g) {
          int dbase = wm + half * 4 + g * 8;
          ushort4 o;
#pragma unroll
          for (int rr = 0; rr < 4; ++rr)
            ((unsigned short*)&o)[rr] = f2bf(1.0f / (1.0f + __expf(-acc[ni][g * 4 + rr])));
          *(ushort4*)&sgb[((size_t)h * S_LEN + scol) * HD + dbase] = o;
        }
      }
    }
  } else if (ty < 36) {
    int hk = ty - 32;
    norm_rope_epi4(acc, pp, kw, pos_ids, cosc, sinc,
                   kbuf + (size_t)hk * S_LEN * HD, wave, lane, wm, scol0);
  } else {
    int hk = ty - 36;  // v: rows are d, cols are s -> vTb (hk,D,S)
#pragma unroll
    for (int ni = 0; ni < 2; ++ni)
#pragma unroll
      for (int reg = 0; reg < 16; ++reg) {
        int d = wm + (reg & 3) + 8 * (reg >> 2) + 4 * half;
        vTb[(size_t)hk * HD * S_LEN + (size_t)d * S_LEN + scol0 + ni * 32 + l31] =
            f2bf(acc[ni][reg]);
      }
  }
}

// ---------------- O-proj GEMM 64x64, 2 waves, DMA-staged 2-buffer (R14) -----
#define STAGE_O2(B_, KT)                                                       \
  { _Pragma("unroll")                                                          \
    for (int i = 0; i < 4; ++i) {                                              \
      int row = wm + i * 8 + sr;                                               \
      async_copy16(Ag + (size_t)row * C_DIM + (KT) + (sc ^ swz8(row)) * 8,     \
                   &Asm[B_][(wm + i * 8) * 64]);                               \
    }                                                                          \
    _Pragma("unroll")                                                          \
    for (int i = 0; i < 4; ++i) {                                              \
      int row = wm + i * 8 + sr;                                               \
      async_copy16(Bg + (size_t)row * C_DIM + (KT) + (sc ^ swz8(row)) * 8,     \
                   &Bsm[B_][(wm + i * 8) * 64]);                               \
    } }

__global__ __launch_bounds__(128, 2)
void gemm_oproj(const unsigned short* __restrict__ A,
                const unsigned short* __restrict__ BT,
                float* __restrict__ C) {
  __shared__ unsigned short Asm[2][64 * 64];
  __shared__ unsigned short Bsm[2][64 * 64];
  int tid = threadIdx.x, wave = tid >> 6, lane = tid & 63;
  int l31 = lane & 31, half = lane >> 5;
  int wm = wave * 32;
  int m0 = blockIdx.x * 64, n0 = blockIdx.y * 64;
  int sr = lane >> 3, sc = lane & 7;
  const unsigned short* Ag = A + (size_t)m0 * C_DIM;
  const unsigned short* Bg = BT + (size_t)n0 * C_DIM;
  int aswz = swz8(wm + l31);
  int bswz0 = swz8(l31), bswz1 = swz8(32 + l31);
  floatx16 acc[2];
  acc[0] = (floatx16)0.f; acc[1] = (floatx16)0.f;

  STAGE_O2(0, 0)
  STAGE_O2(1, 64)

  for (int t = 0; t < 32; ++t) {
    int b = t & 1;
    if (t < 31) { WAIT_VM(8); } else { WAIT_VM(0); }  // tile t landed; t+1 flying
    __builtin_amdgcn_s_barrier();
    __builtin_amdgcn_s_setprio(1);
#pragma unroll
    for (int kb = 0; kb < 4; ++kb) {
      int c2 = (kb << 1) | half;
      bf16x8 av  = *(const bf16x8*)&Asm[b][(wm + l31) * 64 + ((c2 ^ aswz) << 3)];
      bf16x8 b0v = *(const bf16x8*)&Bsm[b][l31 * 64 + ((c2 ^ bswz0) << 3)];
      bf16x8 b1v = *(const bf16x8*)&Bsm[b][(32 + l31) * 64 + ((c2 ^ bswz1) << 3)];
      acc[0] = __builtin_amdgcn_mfma_f32_32x32x16_bf16(av, b0v, acc[0], 0, 0, 0);
      acc[1] = __builtin_amdgcn_mfma_f32_32x32x16_bf16(av, b1v, acc[1], 0, 0, 0);
    }
    __builtin_amdgcn_s_setprio(0);
    bar_lds_only();                    // both waves done reading buf b
    if (t < 30) STAGE_O2(b, (t + 2) * 64)
  }

#pragma unroll
  for (int ni = 0; ni < 2; ++ni)
#pragma unroll
    for (int reg = 0; reg < 16; ++reg) {
      int row = m0 + wm + (reg & 3) + 8 * (reg >> 2) + 4 * half;
      C[(size_t)row * S_LEN + n0 + ni * 32 + l31] = acc[ni][reg];
    }
}

// ---------------- MFMA flash attention, split-KV x2, direct qt<8 path -------
__global__ __launch_bounds__(256)
void attn_kernel(const unsigned short* __restrict__ qb,
                 const unsigned short* __restrict__ kbuf,
                 const unsigned short* __restrict__ vTb,
                 const unsigned short* __restrict__ sgb,
                 unsigned short* __restrict__ outT,
                 float* __restrict__ pm, float* __restrict__ pl,
                 float* __restrict__ pO0, float* __restrict__ pO1) {
  __shared__ __align__(16) unsigned short Ks[64 * 128];   // [key][d], swizzled
  __shared__ __align__(16) unsigned short Vs[128 * 64];   // [d][key], swizzled
  __shared__ __align__(16) unsigned short Ps[4][16][72];
  int h = blockIdx.x, qt = blockIdx.y, ch = blockIdx.z;
  int t0 = ch * 8;
  if (t0 > qt) return;                    // empty chunk (uniform exit)
  int t1 = min(qt, t0 + 7);
  int vc = (qt >= 8) ? 2 : 1;
  int s0 = qt * 64;
  int hk = h >> 2;
  int tid = threadIdx.x, wave = tid >> 6, lane = tid & 63;
  int l16 = lane & 15, quad = lane >> 4;
  int lsw = l16 & 7;

  const unsigned short* qg = qb + ((size_t)(h * S_LEN + s0 + wave * 16 + l16)) * HD;
  bf16x8 qfr[4];
#pragma unroll
  for (int kb = 0; kb < 4; ++kb)
    qfr[kb] = *(const bf16x8*)(qg + kb * 32 + quad * 8);

  float m_r[4], l_r[4];
#pragma unroll
  for (int r = 0; r < 4; ++r) { m_r[r] = -1e30f; l_r[r] = 0.f; }
  floatx4 acc_o[8];
#pragma unroll
  for (int i = 0; i < 8; ++i) acc_o[i] = (floatx4)0.f;
  int srow_base = s0 + wave * 16 + quad * 4;

  const unsigned short* kg0 = kbuf + (size_t)hk * S_LEN * HD;
  const unsigned short* vg0 = vTb + (size_t)hk * HD * S_LEN;

  int kr4 = lane >> 4, kc16 = lane & 15;
  int vr8 = lane >> 3, vc8 = lane & 7;

  for (int t = t0; t <= t1; ++t) {
    int jt = t * 64;
#pragma unroll
    for (int i = 0; i < 4; ++i) {
      int rbase = wave * 16 + i * 4;
      int row = rbase + kr4;
      int cs = kc16 ^ (row & 7);
      async_copy16(kg0 + (size_t)(jt + row) * HD + cs * 8, Ks + rbase * 128);
    }
#pragma unroll
    for (int i = 0; i < 4; ++i) {
      int rbase = wave * 32 + i * 8;
      int row = rbase + vr8;
      int cs = vc8 ^ (row & 7);
      async_copy16(vg0 + (size_t)row * S_LEN + jt + cs * 8, Vs + rbase * 64);
    }
    __syncthreads();

    floatx4 acc_s[4];
#pragma unroll
    for (int ni = 0; ni < 4; ++ni) acc_s[ni] = (floatx4)0.f;
    __builtin_amdgcn_s_setprio(1);
#pragma unroll
    for (int kb = 0; kb < 4; ++kb) {
#pragma unroll
      for (int ni = 0; ni < 4; ++ni) {
        int cl = (kb * 4 + quad) ^ lsw;
        bf16x8 bk = *(const bf16x8*)&Ks[(ni * 16 + l16) * 128 + cl * 8];
        acc_s[ni] = __builtin_amdgcn_mfma_f32_16x16x32_bf16(qfr[kb], bk, acc_s[ni], 0, 0, 0);
      }
    }
    __builtin_amdgcn_s_setprio(0);

    bool diag = (t == qt);
    float alpha[4];
#pragma unroll
    for (int r = 0; r < 4; ++r) {
      float scv[4];
      float mx = -1e30f;
#pragma unroll
      for (int ni = 0; ni < 4; ++ni) {
        float sv = acc_s[ni][r] * SCALE;
        if (diag) {
          int jg = jt + ni * 16 + l16;
          if (jg > srow_base + r) sv = -1e30f;
        }
        scv[ni] = sv;
        mx = fmaxf(mx, sv);
      }
#pragma unroll
      for (int off = 8; off; off >>= 1) mx = fmaxf(mx, __shfl_xor(mx, off, 16));
      float mnew = fmaxf(m_r[r], mx);
      float psv = 0.f;
#pragma unroll
      for (int ni = 0; ni < 4; ++ni) {
        float pv = (scv[ni] > -1e29f) ? __expf(scv[ni] - mnew) : 0.f;
        Ps[wave][quad * 4 + r][ni * 16 + l16] = f2bf(pv);
        psv += pv;
      }
#pragma unroll
      for (int off = 8; off; off >>= 1) psv += __shfl_xor(psv, off, 16);
      alpha[r] = __expf(m_r[r] - mnew);
      m_r[r] = mnew;
      l_r[r] = l_r[r] * alpha[r] + psv;
    }
#pragma unroll
    for (int i = 0; i < 8; ++i)
#pragma unroll
      for (int r = 0; r < 4; ++r) acc_o[i][r] *= alpha[r];
    __threadfence_block();

    __builtin_amdgcn_s_setprio(1);
#pragma unroll
    for (int kb2 = 0; kb2 < 2; ++kb2) {
      bf16x8 ap = *(const bf16x8*)&Ps[wave][l16][kb2 * 32 + quad * 8];
#pragma unroll
      for (int ni2 = 0; ni2 < 8; ++ni2) {
        int cl = (kb2 * 4 + quad) ^ lsw;
        bf16x8 bv = *(const bf16x8*)&Vs[(ni2 * 16 + l16) * 64 + cl * 8];
        acc_o[ni2] = __builtin_amdgcn_mfma_f32_16x16x32_bf16(ap, bv, acc_o[ni2], 0, 0, 0);
      }
    }
    __builtin_amdgcn_s_setprio(0);
    __syncthreads();
  }

  if (vc == 1) {
    // qt<8: single chunk covers the whole causal range -- finish directly
#pragma unroll
    for (int r = 0; r < 4; ++r) {
      int s = srow_base + r;
      float inv = 1.0f / l_r[r];
      const unsigned short* sgp = sgb + ((size_t)h * S_LEN + s) * HD;
      unsigned short* op = outT + (size_t)s * (NH * HD) + h * HD;
#pragma unroll
      for (int ni2 = 0; ni2 < 8; ++ni2) {
        int d = ni2 * 16 + l16;
        op[d] = f2bf(acc_o[ni2][r] * inv * bf2f(sgp[d]));
      }
    }
    return;
  }

  // qt>=8: write (m, l, O) partials; merge kernel combines the 2 chunks
  size_t pr = (size_t)(h * 16 + qt);
  float* pOp = ((ch == 0) ? pO0 : pO1) + pr * 8192;
#pragma unroll
  for (int r = 0; r < 4; ++r) {
    int rrow = wave * 16 + quad * 4 + r;
    if (l16 == 0) { pm[(pr * 2 + ch) * 64 + rrow] = m_r[r]; pl[(pr * 2 + ch) * 64 + rrow] = l_r[r]; }
#pragma unroll
    for (int ni2 = 0; ni2 < 8; ++ni2)
      pOp[rrow * 128 + ni2 * 16 + l16] = acc_o[ni2][r];
  }
}

// ---------------- attn merge: 2-way combine for qt>=8, gate, write outT -----
__global__ __launch_bounds__(256)
void attn_merge(const float* __restrict__ pm, const float* __restrict__ pl,
                const float* __restrict__ pO0, const float* __restrict__ pO1,
                const unsigned short* __restrict__ sgb,
                unsigned short* __restrict__ outT) {
  int h = blockIdx.x, qt = blockIdx.y + 8;   // only qt 8..15 have 2 chunks
  size_t pr = (size_t)(h * 16 + qt);
  const float* O0 = pO0 + pr * 8192;
  const float* O1 = pO1 + pr * 8192;
  int lane32 = threadIdx.x & 31, rb = threadIdx.x >> 5;  // rb 0..7
  int d = lane32 * 4;
#pragma unroll
  for (int rr = 0; rr < 8; ++rr) {
    int row = rr * 8 + rb;
    float m0 = pm[(pr * 2 + 0) * 64 + row], l0 = pl[(pr * 2 + 0) * 64 + row];
    float m1 = pm[(pr * 2 + 1) * 64 + row], l1 = pl[(pr * 2 + 1) * 64 + row];
    float M = fmaxf(m0, m1);
    float w0 = __expf(m0 - M), w1 = __expf(m1 - M);
    float L = w0 * l0 + w1 * l1;
    float inv = 1.0f / L;
    floatx4 o0 = *(const floatx4*)&O0[row * 128 + d];
    floatx4 o1 = *(const floatx4*)&O1[row * 128 + d];
    int s = qt * 64 + row;
    ushort4 sg4 = *(const ushort4*)&sgb[((size_t)h * S_LEN + s) * HD + d];
    ushort4 out4;
#pragma unroll
    for (int j = 0; j < 4; ++j) {
      float v = (o0[j] * w0 + o1[j] * w1) * inv;
      ((unsigned short*)&out4)[j] = f2bf(v * bf2f(((unsigned short*)&sg4)[j]));
    }
    *(ushort4*)&outT[(size_t)s * (NH * HD) + h * HD + d] = out4;
  }
}

// ---------------- host launch (5 dispatches) ----------------
extern "C" void kernel_launch(void* const* d_in, const int* in_sizes, int n_in,
                              void* d_out, int out_size, void* d_ws, size_t ws_size,
                              hipStream_t stream) {
  const float* hs       = (const float*)d_in[0];
  const float* q_proj_w = (const float*)d_in[1];
  const float* k_proj_w = (const float*)d_in[2];
  const float* v_proj_w = (const float*)d_in[3];
  const float* o_proj_w = (const float*)d_in[4];
  const float* q_norm_w = (const float*)d_in[5];
  const float* k_norm_w = (const float*)d_in[6];
  const int*   pos_ids  = (const int*)d_in[9];
  const float* cos_c    = (const float*)d_in[10];
  const float* sin_c    = (const float*)d_in[11];
  float* out = (float*)d_out;

  char* ws = (char*)d_ws;
  unsigned short* wqkv = (unsigned short*)(ws + 0);            // 5120x2048 bf16
  unsigned short* wo   = (unsigned short*)(ws + 20971520);     // 2048x2048 bf16
  unsigned short* xT   = (unsigned short*)(ws + 29360128);     // 1024x2048 bf16
  unsigned short* qb   = (unsigned short*)(ws + 33554432);     // 16x1024x128
  unsigned short* kbuf = (unsigned short*)(ws + 37748736);     // 4x1024x128
  unsigned short* vTb  = (unsigned short*)(ws + 38797312);     // 4x128x1024 (V^T)
  unsigned short* sgb  = (unsigned short*)(ws + 39845888);     // 16x1024x128
  unsigned short* aoT  = (unsigned short*)(ws + 44040192);     // 1024x2048
  // attn partials: chunk 0's pO ALIASES wqkv (dead after gemm_qkv; same-stream
  // ordering), chunk 1 in the R8-proven slot. pm/pl after.
  float*          pO0  = (float*)(ws + 0);                     // 256x8192 f32 (8.4MB)
  float*          pO1  = (float*)(ws + 48234496);              // 256x8192 f32 (8.4MB)
  float*          pm   = (float*)(ws + 65011712);              // 256x2x64 f32
  float*          pl   = (float*)(ws + 65142784);              // 256x2x64 f32

  prep_kernel<<<14336 + 2048, 256, 0, stream>>>(q_proj_w, k_proj_w, v_proj_w, o_proj_w,
                                                wqkv, hs, xT);
  gemm_qkv_fused<<<dim3(40, 16), 256, 0, stream>>>(wqkv, xT, q_norm_w, k_norm_w,
                                                   pos_ids, cos_c, sin_c,
                                                   qb, kbuf, vTb, sgb);
  attn_kernel<<<dim3(16, 16, 2), 256, 0, stream>>>(qb, kbuf, vTb, sgb, aoT,
                                                   pm, pl, pO0, pO1);
  attn_merge<<<dim3(16, 8), 256, 0, stream>>>(pm, pl, pO0, pO1, sgb, aoT);
  gemm_oproj<<<dim3(32, 16), 128, 0, stream>>>(wo, aoT, out);
}

// Round 19
// 224.592 us; speedup vs baseline: 1.0333x; 1.0333x over previous
//
#include <hip/hip_runtime.h>
#include <cstdint>

#define S_LEN 1024
#define C_DIM 2048
#define NH    16
#define NHK   4
#define HD    128
#define ROT   32
#define SCALE 0.08838834764831845f  // 1/sqrt(128)

typedef __bf16 bf16x8 __attribute__((ext_vector_type(8)));
typedef float floatx4 __attribute__((ext_vector_type(4)));
typedef float floatx16 __attribute__((ext_vector_type(16)));
typedef unsigned short ushortx8 __attribute__((ext_vector_type(8)));

__device__ __forceinline__ unsigned short f2bf(float f) {
  union { float f; uint32_t u; } x; x.f = f;
  uint32_t r = (x.u + 0x7fffu + ((x.u >> 16) & 1u)) >> 16;
  return (unsigned short)r;
}
__device__ __forceinline__ float bf2f(unsigned short v) {
  union { uint32_t u; float f; } x; x.u = (uint32_t)v << 16; return x.f;
}

__device__ __forceinline__ void async_copy16(const unsigned short* g, unsigned short* l) {
  __builtin_amdgcn_global_load_lds(
      (const __attribute__((address_space(1))) void*)g,
      (__attribute__((address_space(3))) void*)l,
      16, 0, 0);
}

#define WAIT_VM(N) asm volatile("s_waitcnt vmcnt(" #N ")" ::: "memory")

// Barrier that waits ONLY on LDS ops (lgkmcnt) before syncing; DMA (vmcnt)
// stays in flight across it unless explicitly counted beforehand.
__device__ __forceinline__ void bar_lds_only() {
  asm volatile("s_waitcnt lgkmcnt(0)" ::: "memory");
  __builtin_amdgcn_s_barrier();
}

// Bank swizzle: separates rows {r, r+8, r+16, r+24} -> conflict-free (R7: took
// SQ_LDS_BANK_CONFLICT 3.9M -> 0). Bijective per row.
__device__ __forceinline__ int swz8(int row) { return (row ^ (row >> 3)) & 7; }

// ---------------- merged prep: weight cast + x transpose (1 dispatch) -------
__global__ __launch_bounds__(256)
void prep_kernel(const float* __restrict__ qw, const float* __restrict__ kw,
                 const float* __restrict__ vw, const float* __restrict__ ow,
                 unsigned short* __restrict__ wout,
                 const float* __restrict__ x, unsigned short* __restrict__ xT) {
  __shared__ float t[32][33];
  int bid = blockIdx.x;
  if (bid < 14336) {
    const int NQ = 4096 * 2048 / 4, NK = 512 * 2048 / 4, NV = 512 * 2048 / 4;
    int i = bid * 256 + threadIdx.x;
    const float* src; int j;
    if (i < NQ) { src = qw; j = i; }
    else if (i < NQ + NK) { src = kw; j = i - NQ; }
    else if (i < NQ + NK + NV) { src = vw; j = i - NQ - NK; }
    else { src = ow; j = i - NQ - NK - NV; }
    float4 v = ((const float4*)src)[j];
    ushort4 o;
    o.x = f2bf(v.x); o.y = f2bf(v.y); o.z = f2bf(v.z); o.w = f2bf(v.w);
    ((ushort4*)wout)[i] = o;
  } else {
    int b2 = bid - 14336;
    int st = b2 & 31, ct = b2 >> 5;
    int c = threadIdx.x & 31, rq = threadIdx.x >> 5;
#pragma unroll
    for (int i = 0; i < 4; ++i) {
      int r = rq + i * 8;
      t[r][c] = x[(size_t)(ct * 32 + r) * S_LEN + st * 32 + c];
    }
    __syncthreads();
#pragma unroll
    for (int i = 0; i < 4; ++i) {
      int r = rq + i * 8;
      xT[(size_t)(st * 32 + r) * C_DIM + ct * 32 + c] = f2bf(t[c][r]);
    }
  }
}

// ---------------- RMSNorm+RoPE epilogue (4-wave core, 2 ni per wave) --------
__device__ __forceinline__ void norm_rope_epi4(
    floatx16 (&acc)[2], float (*pp)[64],
    const float* __restrict__ w, const int* __restrict__ pos_ids,
    const float* __restrict__ cosc, const float* __restrict__ sinc,
    unsigned short* __restrict__ outp,  // (S, D) for this head
    int wave, int lane, int wm, int scol0) {
  int l31 = lane & 31, half = lane >> 5;
#pragma unroll
  for (int ni = 0; ni < 2; ++ni) {
    float s = 0.f;
#pragma unroll
    for (int reg = 0; reg < 16; ++reg) { float v = acc[ni][reg]; s += v * v; }
    s += __shfl_xor(s, 32);
    if (half == 0) pp[wave][ni * 32 + l31] = s;
  }
  __syncthreads();
#pragma unroll
  for (int ni = 0; ni < 2; ++ni) {
    int ci = ni * 32 + l31;
    float tot = pp[0][ci] + pp[1][ci] + pp[2][ci] + pp[3][ci];
    float rn = rsqrtf(tot * (1.0f / 128.0f) + 1e-6f);
    int scol = scol0 + ni * 32 + l31;
    int pos = pos_ids[scol];
    bool rope = (wm == 0);  // wave 0 covers d 0..31
#pragma unroll
    for (int g = 0; g < 4; ++g) {
      int dbase = wm + half * 4 + g * 8;
      ushort4 o;
#pragma unroll
      for (int rr = 0; rr < 4; ++rr) {
        int reg = g * 4 + rr;
        int d = dbase + rr;
        float v = acc[ni][reg] * rn * (1.0f + w[d]);
        if (rope) {
          float cv = cosc[pos * ROT + d], sv = sinc[pos * ROT + d];
          int d2 = (d < 16) ? d + 16 : d - 16;
          float pv = acc[ni][reg ^ 8] * rn * (1.0f + w[d2]);  // row +-16
          v = v * cv + ((d < 16) ? -pv : pv) * sv;
        }
        ((unsigned short*)&o)[rr] = f2bf(v);
      }
      *(ushort4*)&outp[(size_t)scol * HD + dbase] = o;
    }
  }
}

// ---------------- QKV GEMM 128x64, 4 waves, DMA-staged 2-buffer (R12) -------
// R17-final: 40.7us, conflicts 0, FETCH 27.5MB. R18's setprio variant
// regressed (44.7us) -- with 2-3 blocks/CU all waves sit in the same prio-1
// MFMA window, so the hint only adds SALU overhead (matches m190's GEMM
// null). This 2-buffer stage(t+2) schedule is the measured local optimum.
#define STAGE_QKV4(B_, KT)                                                     \
  { _Pragma("unroll")                                                          \
    for (int i = 0; i < 4; ++i) {                                              \
      int row = wm + i * 8 + sr;                                               \
      async_copy16(Ag + (size_t)row * C_DIM + (KT) + (sc ^ swz8(row)) * 8,     \
                   &Asm[B_][(wm + i * 8) * 64]);                               \
    }                                                                          \
    _Pragma("unroll")                                                          \
    for (int i = 0; i < 2; ++i) {                                              \
      int row = wave * 16 + i * 8 + sr;                                        \
      async_copy16(Bg + (size_t)row * C_DIM + (KT) + (sc ^ swz8(row)) * 8,     \
                   &Bsm[B_][(wave * 16 + i * 8) * 64]);                        \
    } }

__global__ __launch_bounds__(256, 3)
void gemm_qkv_fused(const unsigned short* __restrict__ A,
                    const unsigned short* __restrict__ BT,
                    const float* __restrict__ qw, const float* __restrict__ kw,
                    const int* __restrict__ pos_ids,
                    const float* __restrict__ cosc, const float* __restrict__ sinc,
                    unsigned short* __restrict__ qb, unsigned short* __restrict__ kbuf,
                    unsigned short* __restrict__ vTb, unsigned short* __restrict__ sgb) {
  __shared__ unsigned short Asm[2][128 * 64];
  __shared__ unsigned short Bsm[2][64 * 64];
  __shared__ float pp[4][64];
  int tid = threadIdx.x, wave = tid >> 6, lane = tid & 63;
  int l31 = lane & 31, half = lane >> 5;
  int wm = wave * 32;
  int m0 = blockIdx.x * 128, n0 = blockIdx.y * 64;
  int sr = lane >> 3, sc = lane & 7;
  const unsigned short* Ag = A + (size_t)m0 * C_DIM;
  const unsigned short* Bg = BT + (size_t)n0 * C_DIM;
  int aswz = swz8(wm + l31);
  int bswz0 = swz8(l31), bswz1 = swz8(32 + l31);
  floatx16 acc[2];
  acc[0] = (floatx16)0.f; acc[1] = (floatx16)0.f;

  STAGE_QKV4(0, 0)
  STAGE_QKV4(1, 64)

  for (int t = 0; t < 32; ++t) {
    int b = t & 1;
    if (t < 31) { WAIT_VM(6); } else { WAIT_VM(0); }  // tile t landed; t+1 flying
    __builtin_amdgcn_s_barrier();
#pragma unroll
    for (int kb = 0; kb < 4; ++kb) {
      int c2 = (kb << 1) | half;
      bf16x8 av  = *(const bf16x8*)&Asm[b][(wm + l31) * 64 + ((c2 ^ aswz) << 3)];
      bf16x8 b0v = *(const bf16x8*)&Bsm[b][l31 * 64 + ((c2 ^ bswz0) << 3)];
      bf16x8 b1v = *(const bf16x8*)&Bsm[b][(32 + l31) * 64 + ((c2 ^ bswz1) << 3)];
      acc[0] = __builtin_amdgcn_mfma_f32_32x32x16_bf16(av, b0v, acc[0], 0, 0, 0);
      acc[1] = __builtin_amdgcn_mfma_f32_32x32x16_bf16(av, b1v, acc[1], 0, 0, 0);
    }
    bar_lds_only();                    // all waves done reading buf b
    if (t < 30) STAGE_QKV4(b, (t + 2) * 64)
  }

  int scol0 = n0;
  int ty = blockIdx.x;
  if (ty < 32) {
    int h = ty >> 1;
    if ((ty & 1) == 0) {
      norm_rope_epi4(acc, pp, qw, pos_ids, cosc, sinc,
                     qb + (size_t)h * S_LEN * HD, wave, lane, wm, scol0);
    } else {
#pragma unroll
      for (int ni = 0; ni < 2; ++ni) {
        int scol = scol0 + ni * 32 + l31;
#pragma unroll
        for (int g = 0; g < 4; ++g) {
          int dbase = wm + half * 4 + g * 8;
          ushort4 o;
#pragma unroll
          for (int rr = 0; rr < 4; ++rr)
            ((unsigned short*)&o)[rr] = f2bf(1.0f / (1.0f + __expf(-acc[ni][g * 4 + rr])));
          *(ushort4*)&sgb[((size_t)h * S_LEN + scol) * HD + dbase] = o;
        }
      }
    }
  } else if (ty < 36) {
    int hk = ty - 32;
    norm_rope_epi4(acc, pp, kw, pos_ids, cosc, sinc,
                   kbuf + (size_t)hk * S_LEN * HD, wave, lane, wm, scol0);
  } else {
    int hk = ty - 36;  // v: rows are d, cols are s -> vTb (hk,D,S)
#pragma unroll
    for (int ni = 0; ni < 2; ++ni)
#pragma unroll
      for (int reg = 0; reg < 16; ++reg) {
        int d = wm + (reg & 3) + 8 * (reg >> 2) + 4 * half;
        vTb[(size_t)hk * HD * S_LEN + (size_t)d * S_LEN + scol0 + ni * 32 + l31] =
            f2bf(acc[ni][reg]);
      }
  }
}

// ---------------- O-proj GEMM 64x64, 2 waves, DMA-staged 2-buffer (R14) -----
#define STAGE_O2(B_, KT)                                                       \
  { _Pragma("unroll")                                                          \
    for (int i = 0; i < 4; ++i) {                                              \
      int row = wm + i * 8 + sr;                                               \
      async_copy16(Ag + (size_t)row * C_DIM + (KT) + (sc ^ swz8(row)) * 8,     \
                   &Asm[B_][(wm + i * 8) * 64]);                               \
    }                                                                          \
    _Pragma("unroll")                                                          \
    for (int i = 0; i < 4; ++i) {                                              \
      int row = wm + i * 8 + sr;                                               \
      async_copy16(Bg + (size_t)row * C_DIM + (KT) + (sc ^ swz8(row)) * 8,     \
                   &Bsm[B_][(wm + i * 8) * 64]);                               \
    } }

__global__ __launch_bounds__(128, 2)
void gemm_oproj(const unsigned short* __restrict__ A,
                const unsigned short* __restrict__ BT,
                float* __restrict__ C) {
  __shared__ unsigned short Asm[2][64 * 64];
  __shared__ unsigned short Bsm[2][64 * 64];
  int tid = threadIdx.x, wave = tid >> 6, lane = tid & 63;
  int l31 = lane & 31, half = lane >> 5;
  int wm = wave * 32;
  int m0 = blockIdx.x * 64, n0 = blockIdx.y * 64;
  int sr = lane >> 3, sc = lane & 7;
  const unsigned short* Ag = A + (size_t)m0 * C_DIM;
  const unsigned short* Bg = BT + (size_t)n0 * C_DIM;
  int aswz = swz8(wm + l31);
  int bswz0 = swz8(l31), bswz1 = swz8(32 + l31);
  floatx16 acc[2];
  acc[0] = (floatx16)0.f; acc[1] = (floatx16)0.f;

  STAGE_O2(0, 0)
  STAGE_O2(1, 64)

  for (int t = 0; t < 32; ++t) {
    int b = t & 1;
    if (t < 31) { WAIT_VM(8); } else { WAIT_VM(0); }  // tile t landed; t+1 flying
    __builtin_amdgcn_s_barrier();
#pragma unroll
    for (int kb = 0; kb < 4; ++kb) {
      int c2 = (kb << 1) | half;
      bf16x8 av  = *(const bf16x8*)&Asm[b][(wm + l31) * 64 + ((c2 ^ aswz) << 3)];
      bf16x8 b0v = *(const bf16x8*)&Bsm[b][l31 * 64 + ((c2 ^ bswz0) << 3)];
      bf16x8 b1v = *(const bf16x8*)&Bsm[b][(32 + l31) * 64 + ((c2 ^ bswz1) << 3)];
      acc[0] = __builtin_amdgcn_mfma_f32_32x32x16_bf16(av, b0v, acc[0], 0, 0, 0);
      acc[1] = __builtin_amdgcn_mfma_f32_32x32x16_bf16(av, b1v, acc[1], 0, 0, 0);
    }
    bar_lds_only();                    // both waves done reading buf b
    if (t < 30) STAGE_O2(b, (t + 2) * 64)
  }

#pragma unroll
  for (int ni = 0; ni < 2; ++ni)
#pragma unroll
    for (int reg = 0; reg < 16; ++reg) {
      int row = m0 + wm + (reg & 3) + 8 * (reg >> 2) + 4 * half;
      C[(size_t)row * S_LEN + n0 + ni * 32 + l31] = acc[ni][reg];
    }
}

// ---------------- MFMA flash attention, split-KV x2, direct qt<8 path -------
__global__ __launch_bounds__(256)
void attn_kernel(const unsigned short* __restrict__ qb,
                 const unsigned short* __restrict__ kbuf,
                 const unsigned short* __restrict__ vTb,
                 const unsigned short* __restrict__ sgb,
                 unsigned short* __restrict__ outT,
                 float* __restrict__ pm, float* __restrict__ pl,
                 float* __restrict__ pO0, float* __restrict__ pO1) {
  __shared__ __align__(16) unsigned short Ks[64 * 128];   // [key][d], swizzled
  __shared__ __align__(16) unsigned short Vs[128 * 64];   // [d][key], swizzled
  __shared__ __align__(16) unsigned short Ps[4][16][72];
  int h = blockIdx.x, qt = blockIdx.y, ch = blockIdx.z;
  int t0 = ch * 8;
  if (t0 > qt) return;                    // empty chunk (uniform exit)
  int t1 = min(qt, t0 + 7);
  int vc = (qt >= 8) ? 2 : 1;
  int s0 = qt * 64;
  int hk = h >> 2;
  int tid = threadIdx.x, wave = tid >> 6, lane = tid & 63;
  int l16 = lane & 15, quad = lane >> 4;
  int lsw = l16 & 7;

  const unsigned short* qg = qb + ((size_t)(h * S_LEN + s0 + wave * 16 + l16)) * HD;
  bf16x8 qfr[4];
#pragma unroll
  for (int kb = 0; kb < 4; ++kb)
    qfr[kb] = *(const bf16x8*)(qg + kb * 32 + quad * 8);

  float m_r[4], l_r[4];
#pragma unroll
  for (int r = 0; r < 4; ++r) { m_r[r] = -1e30f; l_r[r] = 0.f; }
  floatx4 acc_o[8];
#pragma unroll
  for (int i = 0; i < 8; ++i) acc_o[i] = (floatx4)0.f;
  int srow_base = s0 + wave * 16 + quad * 4;

  const unsigned short* kg0 = kbuf + (size_t)hk * S_LEN * HD;
  const unsigned short* vg0 = vTb + (size_t)hk * HD * S_LEN;

  int kr4 = lane >> 4, kc16 = lane & 15;
  int vr8 = lane >> 3, vc8 = lane & 7;

  for (int t = t0; t <= t1; ++t) {
    int jt = t * 64;
#pragma unroll
    for (int i = 0; i < 4; ++i) {
      int rbase = wave * 16 + i * 4;
      int row = rbase + kr4;
      int cs = kc16 ^ (row & 7);
      async_copy16(kg0 + (size_t)(jt + row) * HD + cs * 8, Ks + rbase * 128);
    }
#pragma unroll
    for (int i = 0; i < 4; ++i) {
      int rbase = wave * 32 + i * 8;
      int row = rbase + vr8;
      int cs = vc8 ^ (row & 7);
      async_copy16(vg0 + (size_t)row * S_LEN + jt + cs * 8, Vs + rbase * 64);
    }
    __syncthreads();

    floatx4 acc_s[4];
#pragma unroll
    for (int ni = 0; ni < 4; ++ni) acc_s[ni] = (floatx4)0.f;
#pragma unroll
    for (int kb = 0; kb < 4; ++kb) {
#pragma unroll
      for (int ni = 0; ni < 4; ++ni) {
        int cl = (kb * 4 + quad) ^ lsw;
        bf16x8 bk = *(const bf16x8*)&Ks[(ni * 16 + l16) * 128 + cl * 8];
        acc_s[ni] = __builtin_amdgcn_mfma_f32_16x16x32_bf16(qfr[kb], bk, acc_s[ni], 0, 0, 0);
      }
    }

    bool diag = (t == qt);
    float alpha[4];
#pragma unroll
    for (int r = 0; r < 4; ++r) {
      float scv[4];
      float mx = -1e30f;
#pragma unroll
      for (int ni = 0; ni < 4; ++ni) {
        float sv = acc_s[ni][r] * SCALE;
        if (diag) {
          int jg = jt + ni * 16 + l16;
          if (jg > srow_base + r) sv = -1e30f;
        }
        scv[ni] = sv;
        mx = fmaxf(mx, sv);
      }
#pragma unroll
      for (int off = 8; off; off >>= 1) mx = fmaxf(mx, __shfl_xor(mx, off, 16));
      float mnew = fmaxf(m_r[r], mx);
      float psv = 0.f;
#pragma unroll
      for (int ni = 0; ni < 4; ++ni) {
        float pv = (scv[ni] > -1e29f) ? __expf(scv[ni] - mnew) : 0.f;
        Ps[wave][quad * 4 + r][ni * 16 + l16] = f2bf(pv);
        psv += pv;
      }
#pragma unroll
      for (int off = 8; off; off >>= 1) psv += __shfl_xor(psv, off, 16);
      alpha[r] = __expf(m_r[r] - mnew);
      m_r[r] = mnew;
      l_r[r] = l_r[r] * alpha[r] + psv;
    }
#pragma unroll
    for (int i = 0; i < 8; ++i)
#pragma unroll
      for (int r = 0; r < 4; ++r) acc_o[i][r] *= alpha[r];
    __threadfence_block();

#pragma unroll
    for (int kb2 = 0; kb2 < 2; ++kb2) {
      bf16x8 ap = *(const bf16x8*)&Ps[wave][l16][kb2 * 32 + quad * 8];
#pragma unroll
      for (int ni2 = 0; ni2 < 8; ++ni2) {
        int cl = (kb2 * 4 + quad) ^ lsw;
        bf16x8 bv = *(const bf16x8*)&Vs[(ni2 * 16 + l16) * 64 + cl * 8];
        acc_o[ni2] = __builtin_amdgcn_mfma_f32_16x16x32_bf16(ap, bv, acc_o[ni2], 0, 0, 0);
      }
    }
    __syncthreads();
  }

  if (vc == 1) {
    // qt<8: single chunk covers the whole causal range -- finish directly
#pragma unroll
    for (int r = 0; r < 4; ++r) {
      int s = srow_base + r;
      float inv = 1.0f / l_r[r];
      const unsigned short* sgp = sgb + ((size_t)h * S_LEN + s) * HD;
      unsigned short* op = outT + (size_t)s * (NH * HD) + h * HD;
#pragma unroll
      for (int ni2 = 0; ni2 < 8; ++ni2) {
        int d = ni2 * 16 + l16;
        op[d] = f2bf(acc_o[ni2][r] * inv * bf2f(sgp[d]));
      }
    }
    return;
  }

  // qt>=8: write (m, l, O) partials; merge kernel combines the 2 chunks
  size_t pr = (size_t)(h * 16 + qt);
  float* pOp = ((ch == 0) ? pO0 : pO1) + pr * 8192;
#pragma unroll
  for (int r = 0; r < 4; ++r) {
    int rrow = wave * 16 + quad * 4 + r;
    if (l16 == 0) { pm[(pr * 2 + ch) * 64 + rrow] = m_r[r]; pl[(pr * 2 + ch) * 64 + rrow] = l_r[r]; }
#pragma unroll
    for (int ni2 = 0; ni2 < 8; ++ni2)
      pOp[rrow * 128 + ni2 * 16 + l16] = acc_o[ni2][r];
  }
}

// ---------------- attn merge: 2-way combine for qt>=8, gate, write outT -----
__global__ __launch_bounds__(256)
void attn_merge(const float* __restrict__ pm, const float* __restrict__ pl,
                const float* __restrict__ pO0, const float* __restrict__ pO1,
                const unsigned short* __restrict__ sgb,
                unsigned short* __restrict__ outT) {
  int h = blockIdx.x, qt = blockIdx.y + 8;   // only qt 8..15 have 2 chunks
  size_t pr = (size_t)(h * 16 + qt);
  const float* O0 = pO0 + pr * 8192;
  const float* O1 = pO1 + pr * 8192;
  int lane32 = threadIdx.x & 31, rb = threadIdx.x >> 5;  // rb 0..7
  int d = lane32 * 4;
#pragma unroll
  for (int rr = 0; rr < 8; ++rr) {
    int row = rr * 8 + rb;
    float m0 = pm[(pr * 2 + 0) * 64 + row], l0 = pl[(pr * 2 + 0) * 64 + row];
    float m1 = pm[(pr * 2 + 1) * 64 + row], l1 = pl[(pr * 2 + 1) * 64 + row];
    float M = fmaxf(m0, m1);
    float w0 = __expf(m0 - M), w1 = __expf(m1 - M);
    float L = w0 * l0 + w1 * l1;
    float inv = 1.0f / L;
    floatx4 o0 = *(const floatx4*)&O0[row * 128 + d];
    floatx4 o1 = *(const floatx4*)&O1[row * 128 + d];
    int s = qt * 64 + row;
    ushort4 sg4 = *(const ushort4*)&sgb[((size_t)h * S_LEN + s) * HD + d];
    ushort4 out4;
#pragma unroll
    for (int j = 0; j < 4; ++j) {
      float v = (o0[j] * w0 + o1[j] * w1) * inv;
      ((unsigned short*)&out4)[j] = f2bf(v * bf2f(((unsigned short*)&sg4)[j]));
    }
    *(ushort4*)&outT[(size_t)s * (NH * HD) + h * HD + d] = out4;
  }
}

// ---------------- host launch (5 dispatches) ----------------
extern "C" void kernel_launch(void* const* d_in, const int* in_sizes, int n_in,
                              void* d_out, int out_size, void* d_ws, size_t ws_size,
                              hipStream_t stream) {
  const float* hs       = (const float*)d_in[0];
  const float* q_proj_w = (const float*)d_in[1];
  const float* k_proj_w = (const float*)d_in[2];
  const float* v_proj_w = (const float*)d_in[3];
  const float* o_proj_w = (const float*)d_in[4];
  const float* q_norm_w = (const float*)d_in[5];
  const float* k_norm_w = (const float*)d_in[6];
  const int*   pos_ids  = (const int*)d_in[9];
  const float* cos_c    = (const float*)d_in[10];
  const float* sin_c    = (const float*)d_in[11];
  float* out = (float*)d_out;

  char* ws = (char*)d_ws;
  unsigned short* wqkv = (unsigned short*)(ws + 0);            // 5120x2048 bf16
  unsigned short* wo   = (unsigned short*)(ws + 20971520);     // 2048x2048 bf16
  unsigned short* xT   = (unsigned short*)(ws + 29360128);     // 1024x2048 bf16
  unsigned short* qb   = (unsigned short*)(ws + 33554432);     // 16x1024x128
  unsigned short* kbuf = (unsigned short*)(ws + 37748736);     // 4x1024x128
  unsigned short* vTb  = (unsigned short*)(ws + 38797312);     // 4x128x1024 (V^T)
  unsigned short* sgb  = (unsigned short*)(ws + 39845888);     // 16x1024x128
  unsigned short* aoT  = (unsigned short*)(ws + 44040192);     // 1024x2048
  // attn partials: chunk 0's pO ALIASES wqkv (dead after gemm_qkv; same-stream
  // ordering), chunk 1 in the R8-proven slot. pm/pl after.
  float*          pO0  = (float*)(ws + 0);                     // 256x8192 f32 (8.4MB)
  float*          pO1  = (float*)(ws + 48234496);              // 256x8192 f32 (8.4MB)
  float*          pm   = (float*)(ws + 65011712);              // 256x2x64 f32
  float*          pl   = (float*)(ws + 65142784);              // 256x2x64 f32

  prep_kernel<<<14336 + 2048, 256, 0, stream>>>(q_proj_w, k_proj_w, v_proj_w, o_proj_w,
                                                wqkv, hs, xT);
  gemm_qkv_fused<<<dim3(40, 16), 256, 0, stream>>>(wqkv, xT, q_norm_w, k_norm_w,
                                                   pos_ids, cos_c, sin_c,
                                                   qb, kbuf, vTb, sgb);
  attn_kernel<<<dim3(16, 16, 2), 256, 0, stream>>>(qb, kbuf, vTb, sgb, aoT,
                                                   pm, pl, pO0, pO1);
  attn_merge<<<dim3(16, 8), 256, 0, stream>>>(pm, pl, pO0, pO1, sgb, aoT);
  gemm_oproj<<<dim3(32, 16), 128, 0, stream>>>(wo, aoT, out);
}